// Round 1
// baseline (5477.603 us; speedup 1.0000x reference)
//
#include <hip/hip_runtime.h>

// Fused ConvTranspose3d(32->64,K=5,S=2,P=2) + bias + MaxPool2 + MaxPool3 + channel-sum
// Final out: (16,1,5,10,10) = 8000 floats.
// One block per final output element. Conv tile = 6x6x6 starting at (6od,6oh,6ow).
// Input tile = 5x5x5 per cin starting at (3od-1, 3oh-1, 3ow-1) (zero-pad at -1).
// Tap (kd,kh,kw) contributes to conv voxels with matching parity: each tap hits
// exactly one voxel per 2x2x2 parity-cell (27 cells), at input offset (2-t) per dim
// where k = p + 2t.

#define CIN 32
#define COUT 64

__global__ __launch_bounds__(256) void fused_convt_pool(
    const float* __restrict__ x, const float* __restrict__ w,
    const float* __restrict__ bias, float* __restrict__ out) {
  __shared__ float xs[CIN * 125];    // 16 KB input tile
  __shared__ float ws[COUT * 125];   // 32 KB one-cin weight slab
  __shared__ float red[256];

  const int bi = blockIdx.x;
  const int b  = bi / 500;
  const int r  = bi % 500;
  const int od = r / 100;
  const int oh = (r / 10) % 10;
  const int ow = r % 10;
  const int tid = threadIdx.x;

  // ---- load 5x5x5 input tile per cin, zero-padded below 0 ----
  const int d0 = 3 * od - 1, h0 = 3 * oh - 1, w0 = 3 * ow - 1;
  for (int e = tid; e < CIN * 125; e += 256) {
    const int cin = e / 125, q = e % 125;
    const int id = q / 25, ih = (q / 5) % 5, iw = q % 5;
    const int gd = d0 + id, gh = h0 + ih, gw = w0 + iw;
    float v = 0.f;
    if (gd >= 0 && gh >= 0 && gw >= 0)  // upper bounds in range by construction
      v = x[(((b * CIN + cin) * 16 + gd) * 32 + gh) * 32 + gw];
    xs[e] = v;
  }

  const int cout = tid >> 2;   // 64 couts
  const int vs   = tid & 3;    // 4 cell-slots cover 27 parity-cells (7 each, last padded)

  int cellbase[7];
#pragma unroll
  for (int j = 0; j < 7; ++j) {
    int cell = vs + 4 * j;
    if (cell > 26) cell = 26;                 // duplicate cell 26; max() is idempotent
    const int cd = cell / 9, ch = (cell / 3) % 3, cw = cell % 3;
    cellbase[j] = cd * 25 + ch * 5 + cw;
  }

  float acc[7][8];
#pragma unroll
  for (int j = 0; j < 7; ++j)
#pragma unroll
    for (int p = 0; p < 8; ++p) acc[j][p] = 0.f;

  for (int cin = 0; cin < CIN; ++cin) {
    __syncthreads();  // previous compute done (iter 0: x tile ready too)
    const float* wg = w + cin * (COUT * 125);
    for (int e = tid; e < COUT * 125; e += 256) ws[e] = wg[e];
    __syncthreads();

    const float* xc = xs + cin * 125;
    const float* wc = ws + cout * 125;

#pragma unroll
    for (int pd = 0; pd < 2; ++pd)
#pragma unroll
      for (int ph = 0; ph < 2; ++ph)
#pragma unroll
        for (int pw = 0; pw < 2; ++pw) {
          const int P = pd * 4 + ph * 2 + pw;  // compile-time parity index
          for (int td = 0; td <= 2 - pd; ++td)
            for (int th = 0; th <= 2 - ph; ++th)
              for (int tw = 0; tw <= 2 - pw; ++tw) {
                const float wv =
                    wc[(pd + 2 * td) * 25 + (ph + 2 * th) * 5 + (pw + 2 * tw)];
                const float* xp = xc + (2 - td) * 25 + (2 - th) * 5 + (2 - tw);
#pragma unroll
                for (int j = 0; j < 7; ++j)
                  acc[j][P] = fmaf(wv, xp[cellbase[j]], acc[j][P]);
              }
        }
  }

  // ---- pool: max over this thread's 7 cells x 8 parities ----
  float m = acc[0][0];
#pragma unroll
  for (int j = 0; j < 7; ++j)
#pragma unroll
    for (int p = 0; p < 8; ++p) m = fmaxf(m, acc[j][p]);
  red[tid] = m;
  __syncthreads();

  // max across 4 slots per cout, +bias, then sum over 64 couts (wave 0)
  if (tid < 64) {
    float cm = fmaxf(fmaxf(red[tid * 4 + 0], red[tid * 4 + 1]),
                     fmaxf(red[tid * 4 + 2], red[tid * 4 + 3]));
    cm += bias[tid];
    for (int off = 32; off > 0; off >>= 1) cm += __shfl_down(cm, off);
    if (tid == 0) out[bi] = cm;
  }
}

extern "C" void kernel_launch(void* const* d_in, const int* in_sizes, int n_in,
                              void* d_out, int out_size, void* d_ws, size_t ws_size,
                              hipStream_t stream) {
  const float* x    = (const float*)d_in[0];
  const float* wgt  = (const float*)d_in[1];
  const float* bias = (const float*)d_in[2];
  float* out = (float*)d_out;
  // grid = B * 5 * 10 * 10 = 8000 blocks
  fused_convt_pool<<<8000, 256, 0, stream>>>(x, wgt, bias, out);
}

// Round 2
// 216.801 us; speedup vs baseline: 25.2656x; 25.2656x over previous
//
#include <hip/hip_runtime.h>
#include <hip/hip_bf16.h>

// ConvTranspose3d(32->64,K=5,S=2,P=2)+bias+MaxPool2+MaxPool3+channel-sum, MFMA version.
// Grid: 1000 blocks = 2 batch-groups x 500 spatial outputs; 8 batches/block.
// Per block: stage x tile (8b x 32cin x 5^3) as bf16 xs_t[b][pos][cin] (pos stride 40
// elems = 80B, conflict-balanced), then per parity p (8): accumulate taps of p via
// mfma_f32_16x16x32_bf16 (M=cout tiles, N=cell columns, K=cin=32 per tap), max-merge
// into mreg, finally cross-lane max over cells + bias + cout-sum.
// Weights pre-reordered to A-fragment order in d_ws by reorder_w (bf16).

typedef __attribute__((ext_vector_type(8))) short short8;
typedef __attribute__((ext_vector_type(4))) float f32x4;

#define CIN 32
#define COUT 64

static __device__ __forceinline__ short f2bf(float f) {
  unsigned u = __float_as_uint(f);
  unsigned r = (u + 0x7fffu + ((u >> 16) & 1u)) >> 16;  // RNE
  return (short)r;
}

// Wr[tap][mtile][lane][j] = bf16(W[cin=8*(lane>>4)+j][cout=16*mtile+(lane&15)][tap])
__global__ __launch_bounds__(256) void reorder_w(const float* __restrict__ w,
                                                 short* __restrict__ wr) {
  const int t = blockIdx.x * 256 + threadIdx.x;  // 0..31999
  const int l = t & 63, mt = (t >> 6) & 3, tap = t >> 8;
  const int cout = 16 * mt + (l & 15);
  const int kb = l >> 4;
  short8 v;
#pragma unroll
  for (int j = 0; j < 8; ++j) {
    const int cin = 8 * kb + j;
    v[j] = f2bf(w[(cin * COUT + cout) * 125 + tap]);
  }
  *(short8*)&wr[t * 8] = v;
}

// cell->column permutation (pos = cd*25+ch*5+cw), residue-balanced mod 8 for banks.
// even tile (cols 0-15) and odd tile (16-31, 11 real + 5 dupes; dupes harmless for max)
#define E0 (0ULL | 1ULL<<6 | 2ULL<<12 | 27ULL<<18 | 52ULL<<24 | 5ULL<<30 | 6ULL<<36 | 7ULL<<42)
#define E1 (32ULL | 25ULL<<6 | 26ULL<<12 | 51ULL<<18 | 12ULL<<24 | 37ULL<<30 | 30ULL<<36 | 55ULL<<42)
#define O0 (56ULL | 57ULL<<6 | 50ULL<<12 | 11ULL<<18 | 36ULL<<24 | 61ULL<<30 | 62ULL<<36 | 31ULL<<42)
#define O1 (0ULL | 1ULL<<6 | 10ULL<<12 | 35ULL<<18 | 60ULL<<24 | 5ULL<<30 | 6ULL<<36 | 7ULL<<42)

__global__ __launch_bounds__(256) void convt_mfma(const float* __restrict__ x,
                                                  const short* __restrict__ wr,
                                                  const float* __restrict__ bias,
                                                  float* __restrict__ out) {
  __shared__ short xs[8 * 5000];  // 80000 B: [b][pos(40 stride)][cin]
  __shared__ float red[16];

  const int bi = blockIdx.x;
  const int bg = bi / 500, r = bi % 500;
  const int od = r / 100, oh = (r / 10) % 10, ow = r % 10;
  const int tid = threadIdx.x;
  const int d0 = 3 * od - 1, h0 = 3 * oh - 1, w0 = 3 * ow - 1;

  // ---- stage x -> bf16 transposed tile ----
  for (int e = tid; e < 8 * CIN * 125; e += 256) {
    const int bb = e / 4000, rem = e % 4000, cin = rem / 125, pos = rem % 125;
    const int id = pos / 25, ih = (pos / 5) % 5, iw = pos % 5;
    const int gd = d0 + id, gh = h0 + ih, gw = w0 + iw;
    float v = 0.f;
    if (gd >= 0 && gh >= 0 && gw >= 0)
      v = x[(((bg * 8 + bb) * CIN + cin) * 16 + gd) * 1024 + gh * 32 + gw];
    xs[bb * 5000 + pos * 40 + cin] = f2bf(v);
  }
  __syncthreads();

  const int lane = tid & 63, wv = tid >> 6;
  const int mhat = wv >> 1, nh = wv & 1;  // cout-half, batch-half
  const int kb = lane >> 4, c = lane & 15;

  const int pos_e = (int)((c < 8 ? (E0 >> (6 * c)) : (E1 >> (6 * (c - 8)))) & 63ULL);
  const int pos_o = (int)((c < 8 ? (O0 >> (6 * c)) : (O1 >> (6 * (c - 8)))) & 63ULL);

  int addr0[8];
#pragma unroll
  for (int i = 0; i < 8; ++i)
    addr0[i] = (4 * nh + (i >> 1)) * 5000 + ((i & 1) ? pos_o : pos_e) * 40 + kb * 8;

  float mreg[2][4][4];
#pragma unroll
  for (int mm = 0; mm < 2; ++mm)
#pragma unroll
    for (int b2 = 0; b2 < 4; ++b2)
#pragma unroll
      for (int q = 0; q < 4; ++q) mreg[mm][b2][q] = -__builtin_inff();

  const short* __restrict__ wbase = wr + (2 * mhat) * 512 + lane * 8;

#pragma unroll 1
  for (int p = 0; p < 8; ++p) {
    const int pd = p >> 2, ph = (p >> 1) & 1, pw = p & 1;
    f32x4 acc[2][8];
#pragma unroll
    for (int mm = 0; mm < 2; ++mm)
#pragma unroll
      for (int i = 0; i < 8; ++i) acc[mm][i] = (f32x4){0.f, 0.f, 0.f, 0.f};

#pragma unroll 1
    for (int td = 0; td <= 2 - pd; ++td)
#pragma unroll 1
      for (int th = 0; th <= 2 - ph; ++th)
        for (int tw = 0; tw <= 2 - pw; ++tw) {
          const int tap = (pd + 2 * td) * 25 + (ph + 2 * th) * 5 + (pw + 2 * tw);
          const int toff40 = ((2 - td) * 25 + (2 - th) * 5 + (2 - tw)) * 40;
          short8 af[2];
#pragma unroll
          for (int mm = 0; mm < 2; ++mm)
            af[mm] = *(const short8*)(wbase + tap * 2048 + mm * 512);
          short8 bfr[8];
#pragma unroll
          for (int i = 0; i < 8; ++i)
            bfr[i] = *(const short8*)&xs[addr0[i] + toff40];
#pragma unroll
          for (int mm = 0; mm < 2; ++mm)
#pragma unroll
            for (int i = 0; i < 8; ++i)
              acc[mm][i] = __builtin_amdgcn_mfma_f32_16x16x32_bf16(
                  af[mm], bfr[i], acc[mm][i], 0, 0, 0);
        }

#pragma unroll
    for (int mm = 0; mm < 2; ++mm)
#pragma unroll
      for (int b2 = 0; b2 < 4; ++b2)
#pragma unroll
        for (int q = 0; q < 4; ++q)
          mreg[mm][b2][q] = fmaxf(mreg[mm][b2][q],
                                  fmaxf(acc[mm][2 * b2][q], acc[mm][2 * b2 + 1][q]));
  }

  // ---- epilogue: max over cells (lanes 0-15 bits), +bias, sum over couts ----
  float S[4];
#pragma unroll
  for (int b2 = 0; b2 < 4; ++b2) {
    float s = 0.f;
#pragma unroll
    for (int mm = 0; mm < 2; ++mm)
#pragma unroll
      for (int q = 0; q < 4; ++q) {
        float v = mreg[mm][b2][q];
        v = fmaxf(v, __shfl_xor(v, 1));
        v = fmaxf(v, __shfl_xor(v, 2));
        v = fmaxf(v, __shfl_xor(v, 4));
        v = fmaxf(v, __shfl_xor(v, 8));
        s += v + bias[32 * mhat + 16 * mm + 4 * kb + q];
      }
    s += __shfl_xor(s, 16);  // sum over kb groups (each holds 8 distinct couts)
    s += __shfl_xor(s, 32);
    S[b2] = s;
  }
  if (lane == 0) {
#pragma unroll
    for (int b2 = 0; b2 < 4; ++b2) red[mhat * 8 + nh * 4 + b2] = S[b2];
  }
  __syncthreads();
  if (tid < 8) {  // tid = nh*4+b2 = local batch
    out[(bg * 8 + tid) * 500 + r] = red[tid] + red[8 + tid];
  }
}

// ---------------- round-1 fallback (used only if ws too small) ----------------
__global__ __launch_bounds__(256) void fused_convt_pool(
    const float* __restrict__ x, const float* __restrict__ w,
    const float* __restrict__ bias, float* __restrict__ out) {
  __shared__ float xsf[CIN * 125];
  __shared__ float ws[COUT * 125];
  __shared__ float red[256];
  const int bi = blockIdx.x;
  const int b = bi / 500;
  const int r = bi % 500;
  const int od = r / 100, oh = (r / 10) % 10, ow = r % 10;
  const int tid = threadIdx.x;
  const int d0 = 3 * od - 1, h0 = 3 * oh - 1, w0 = 3 * ow - 1;
  for (int e = tid; e < CIN * 125; e += 256) {
    const int cin = e / 125, q = e % 125;
    const int id = q / 25, ih = (q / 5) % 5, iw = q % 5;
    const int gd = d0 + id, gh = h0 + ih, gw = w0 + iw;
    float v = 0.f;
    if (gd >= 0 && gh >= 0 && gw >= 0)
      v = x[(((b * CIN + cin) * 16 + gd) * 32 + gh) * 32 + gw];
    xsf[e] = v;
  }
  const int cout = tid >> 2;
  const int vs = tid & 3;
  int cellbase[7];
#pragma unroll
  for (int j = 0; j < 7; ++j) {
    int cell = vs + 4 * j;
    if (cell > 26) cell = 26;
    cellbase[j] = (cell / 9) * 25 + ((cell / 3) % 3) * 5 + cell % 3;
  }
  float acc[7][8];
#pragma unroll
  for (int j = 0; j < 7; ++j)
#pragma unroll
    for (int p = 0; p < 8; ++p) acc[j][p] = 0.f;
  for (int cin = 0; cin < CIN; ++cin) {
    __syncthreads();
    const float* wg = w + cin * (COUT * 125);
    for (int e = tid; e < COUT * 125; e += 256) ws[e] = wg[e];
    __syncthreads();
    const float* xc = xsf + cin * 125;
    const float* wc = ws + cout * 125;
#pragma unroll
    for (int pd = 0; pd < 2; ++pd)
#pragma unroll
      for (int ph = 0; ph < 2; ++ph)
#pragma unroll
        for (int pw = 0; pw < 2; ++pw) {
          const int P = pd * 4 + ph * 2 + pw;
          for (int td = 0; td <= 2 - pd; ++td)
            for (int th = 0; th <= 2 - ph; ++th)
              for (int tw = 0; tw <= 2 - pw; ++tw) {
                const float wv2 =
                    wc[(pd + 2 * td) * 25 + (ph + 2 * th) * 5 + (pw + 2 * tw)];
                const float* xp = xc + (2 - td) * 25 + (2 - th) * 5 + (2 - tw);
#pragma unroll
                for (int j = 0; j < 7; ++j)
                  acc[j][P] = fmaf(wv2, xp[cellbase[j]], acc[j][P]);
              }
        }
  }
  float m = acc[0][0];
#pragma unroll
  for (int j = 0; j < 7; ++j)
#pragma unroll
    for (int p = 0; p < 8; ++p) m = fmaxf(m, acc[j][p]);
  red[tid] = m;
  __syncthreads();
  if (tid < 64) {
    float cm = fmaxf(fmaxf(red[tid * 4 + 0], red[tid * 4 + 1]),
                     fmaxf(red[tid * 4 + 2], red[tid * 4 + 3]));
    cm += bias[tid];
    for (int off = 32; off > 0; off >>= 1) cm += __shfl_down(cm, off);
    if (tid == 0) out[bi] = cm;
  }
}

extern "C" void kernel_launch(void* const* d_in, const int* in_sizes, int n_in,
                              void* d_out, int out_size, void* d_ws, size_t ws_size,
                              hipStream_t stream) {
  const float* x = (const float*)d_in[0];
  const float* wgt = (const float*)d_in[1];
  const float* bias = (const float*)d_in[2];
  float* out = (float*)d_out;
  const size_t wr_bytes = 125 * 4 * 64 * 8 * sizeof(short);  // 512000
  if (ws_size >= wr_bytes) {
    short* wr = (short*)d_ws;
    reorder_w<<<125, 256, 0, stream>>>(wgt, wr);
    convt_mfma<<<1000, 256, 0, stream>>>(x, wr, bias, out);
  } else {
    fused_convt_pool<<<8000, 256, 0, stream>>>(x, wgt, bias, out);
  }
}